// Round 4
// baseline (104.568 us; speedup 1.0000x reference)
//
#include <hip/hip_runtime.h>
#include <hip/hip_bf16.h>

// out[row] = dot(link[row*128 .. +128], theta[0..128)) for row in [0, 1M)
// Memory-bound: 537 MB read / 4 MB write. Strategy: 32 lanes x float4 per row,
// 4 independent row-pairs per wave per iteration (4 KiB contiguous per
// wave-iter, 4 loads in flight), regular (cached) loads — NT-load A/B showed
// it neutral-to-negative — NT only on the tiny output stores.

typedef float f32x4 __attribute__((ext_vector_type(4)));

__global__ __launch_bounds__(256) void linmodel_dot_kernel(
    const float* __restrict__ link,
    const float* __restrict__ theta,
    float* __restrict__ out,
    int num_rows)
{
    const int lane = threadIdx.x & 63;
    const int sub  = lane & 31;   // k-chunk index within row (float4 granularity)
    const int half = lane >> 5;   // which row of each pair this half-wave handles

    const int waveInBlock   = threadIdx.x >> 6;
    const int wavesPerBlock = blockDim.x >> 6;
    const int gwave  = blockIdx.x * wavesPerBlock + waveInBlock;
    const int nwaves = gridDim.x * wavesPerBlock;

    // theta is 128 floats; this lane always dots against chunk `sub`.
    const f32x4 th = reinterpret_cast<const f32x4*>(theta)[sub];

    const f32x4* __restrict__ link4 = reinterpret_cast<const f32x4*>(link);

    // 8 rows per wave per iteration (four independent pairs).
    const int num_octs = num_rows >> 3;

    for (int oct = gwave; oct < num_octs; oct += nwaves) {
        const size_t base = (size_t)oct * 8 + half;

        // Four independent 1 KiB wave-loads, 4 KiB contiguous per wave-iter.
        const f32x4 a0 = link4[(base + 0) * 32 + sub];
        const f32x4 a1 = link4[(base + 2) * 32 + sub];
        const f32x4 a2 = link4[(base + 4) * 32 + sub];
        const f32x4 a3 = link4[(base + 6) * 32 + sub];

        float p0 = a0.x * th.x + a0.y * th.y + a0.z * th.z + a0.w * th.w;
        float p1 = a1.x * th.x + a1.y * th.y + a1.z * th.z + a1.w * th.w;
        float p2 = a2.x * th.x + a2.y * th.y + a2.z * th.z + a2.w * th.w;
        float p3 = a3.x * th.x + a3.y * th.y + a3.z * th.z + a3.w * th.w;

        // Four independent 5-step reductions, interleaved.
        #pragma unroll
        for (int s = 1; s <= 16; s <<= 1) {
            p0 += __shfl_xor(p0, s);
            p1 += __shfl_xor(p1, s);
            p2 += __shfl_xor(p2, s);
            p3 += __shfl_xor(p3, s);
        }

        if (sub == 0) {
            __builtin_nontemporal_store(p0, &out[base + 0]);
            __builtin_nontemporal_store(p1, &out[base + 2]);
            __builtin_nontemporal_store(p2, &out[base + 4]);
            __builtin_nontemporal_store(p3, &out[base + 6]);
        }
    }
}

extern "C" void kernel_launch(void* const* d_in, const int* in_sizes, int n_in,
                              void* d_out, int out_size, void* d_ws, size_t ws_size,
                              hipStream_t stream) {
    const float* link  = (const float*)d_in[0];   // (1024, 1024, 128) f32
    // d_in[1]: route_features — unused by the forward pass
    const float* theta = (const float*)d_in[2];   // (128,) f32
    float* out = (float*)d_out;                   // (1024, 1024) f32

    const int num_rows = out_size;                // 1024*1024

    const int block = 256;
    const int grid  = 2048;  // 8192 waves; 131072 octs -> 16 iters/wave
    linmodel_dot_kernel<<<grid, block, 0, stream>>>(link, theta, out, num_rows);
}

// Round 5
// 99.902 us; speedup vs baseline: 1.0467x; 1.0467x over previous
//
#include <hip/hip_runtime.h>
#include <hip/hip_bf16.h>

// out[row] = dot(link[row*128 .. +128], theta[0..128)) for row in [0, 1M)
// Memory-bound: 537 MB read / 4 MB write per call. Best measured variant
// (R1, 99.9 us): 32 lanes x float4 per row (fully coalesced 1 KiB per wave
// per instruction), one row-pair per wave-iter, shfl_xor reduce, theta float4
// preloaded per-lane. A/B history: +NT loads (R3) = 101.8 us, 4x MLP (R4) =
// 104.6 us -> memory system is saturated; minimal variant wins.

__global__ __launch_bounds__(256) void linmodel_dot_kernel(
    const float* __restrict__ link,
    const float* __restrict__ theta,
    float* __restrict__ out,
    int num_rows)
{
    const int lane = threadIdx.x & 63;
    const int sub  = lane & 31;   // k-chunk index within row (float4 granularity)
    const int half = lane >> 5;   // which row of the pair this half-wave handles

    const int waveInBlock   = threadIdx.x >> 6;
    const int wavesPerBlock = blockDim.x >> 6;
    const int gwave  = blockIdx.x * wavesPerBlock + waveInBlock;
    const int nwaves = gridDim.x * wavesPerBlock;

    // theta is 128 floats; this lane always dots against chunk `sub`.
    const float4 th = reinterpret_cast<const float4*>(theta)[sub];

    const int num_pairs = num_rows >> 1;  // 2 rows per wave per iteration

    for (int pair = gwave; pair < num_pairs; pair += nwaves) {
        const size_t row = (size_t)pair * 2 + half;
        const float4 a = reinterpret_cast<const float4*>(link + row * 128)[sub];

        float p = a.x * th.x + a.y * th.y + a.z * th.z + a.w * th.w;

        // Reduce across the 32 lanes of this half-wave (bits 0..4 only,
        // so the two halves stay independent).
        p += __shfl_xor(p, 1);
        p += __shfl_xor(p, 2);
        p += __shfl_xor(p, 4);
        p += __shfl_xor(p, 8);
        p += __shfl_xor(p, 16);

        if (sub == 0) out[row] = p;
    }
}

extern "C" void kernel_launch(void* const* d_in, const int* in_sizes, int n_in,
                              void* d_out, int out_size, void* d_ws, size_t ws_size,
                              hipStream_t stream) {
    const float* link  = (const float*)d_in[0];   // (1024, 1024, 128) f32
    // d_in[1]: route_features — unused by the forward pass
    const float* theta = (const float*)d_in[2];   // (128,) f32
    float* out = (float*)d_out;                   // (1024, 1024) f32

    const int num_rows = out_size;                // 1024*1024

    const int block = 256;
    const int grid  = 2048;  // 8192 waves = 32/CU, grid-stride over 524288 pairs
    linmodel_dot_kernel<<<grid, block, 0, stream>>>(link, theta, out, num_rows);
}